// Round 13
// baseline (313.237 us; speedup 1.0000x reference)
//
#include <hip/hip_runtime.h>

#define EPS 1e-3f

// ---- prep: fold gamma/beta into W and bias (per band), into d_ws ----
// wp layout: g1 at 0 (8*4*128), g2 at 4096 (12*8*128), g3 at 16384 (8*16*128);
// bp at wp+32768: [28][128] folded bias. Total 145,408 B of d_ws.
__global__ __launch_bounds__(128)
void prep_kernel(const float* __restrict__ g1, const float* __restrict__ be1,
                 const float* __restrict__ W1, const float* __restrict__ b1,
                 const float* __restrict__ g2, const float* __restrict__ be2,
                 const float* __restrict__ W2, const float* __restrict__ b2,
                 const float* __restrict__ g3, const float* __restrict__ be3,
                 const float* __restrict__ W3, const float* __restrict__ b3,
                 float* __restrict__ wp, float* __restrict__ bp)
{
    const int band = blockIdx.x;   // 0..27
    const int d    = threadIdx.x;  // 0..127
    int C, l; const float *W, *ga, *be, *bi; float* wdst;
    if (band < 8)       { C = 4;  l = band;      W = W1; ga = g1; be = be1; bi = b1; wdst = wp + l * 4 * 128; }
    else if (band < 20) { C = 8;  l = band - 8;  W = W2; ga = g2; be = be2; bi = b2; wdst = wp + 4096 + l * 8 * 128; }
    else                { C = 16; l = band - 20; W = W3; ga = g3; be = be3; bi = b3; wdst = wp + 16384 + l * 16 * 128; }
    float acc = bi[l * 128 + d];
    for (int jj = 0; jj < C; ++jj) {
        const float Wv = W[(l * C + jj) * 128 + d];
        wdst[jj * 128 + d] = Wv * ga[l * C + jj];
        acc += be[l * C + jj] * Wv;
    }
    bp[band * 128 + d] = acc;
}

// ---- main: pure streaming, no LDS / no barrier / no shuffles ----
// thread = (band, d4, R consecutive bt rows). W' in registers, x loads are
// uniform per half-wave (L1 broadcast), stats computed redundantly in-thread.
template<int C, int R>
__global__ __launch_bounds__(256)
void bandsplit_stream(const float* __restrict__ x, int BT,
                      const float* __restrict__ wpg,  // group base: [nb][C][128] folded W
                      const float* __restrict__ bp,   // [28][128] folded bias (absolute band)
                      int start0, int band0, int nb,
                      float* __restrict__ out)
{
    const int l     = blockIdx.x % nb;
    const int rt    = blockIdx.x / nb;
    const int band  = band0 + l;
    const int start = start0 + l * C;
    const int tid   = threadIdx.x;
    const int d4    = (tid & 31) * 4;
    const int rg    = tid >> 5;              // 0..7
    const int r0    = rt * (8 * R) + rg * R;

    float4 w[C];
#pragma unroll
    for (int jj = 0; jj < C; ++jj)
        w[jj] = *(const float4*)(wpg + (l * C + jj) * 128 + d4);
    const float4 b4 = *(const float4*)(bp + band * 128 + d4);
    const float inv_c = 1.0f / (float)C;

#pragma unroll
    for (int k = 0; k < R; ++k) {
        const int bt = r0 + k;
        if (bt < BT) {
            const float* xr = x + (size_t)bt * 257 + start;
            float xv[C];
#pragma unroll
            for (int jj = 0; jj < C; ++jj) xv[jj] = xr[jj];
            float s = 0.f, sq = 0.f;
#pragma unroll
            for (int jj = 0; jj < C; ++jj) { s += xv[jj]; sq += xv[jj] * xv[jj]; }
            const float mean = s * inv_c;
            const float var  = sq * inv_c - mean * mean;
            const float rstd = rsqrtf(var + EPS);
            float4 acc = b4;
#pragma unroll
            for (int jj = 0; jj < C; ++jj) {
                const float z = (xv[jj] - mean) * rstd;
                acc.x += z * w[jj].x;
                acc.y += z * w[jj].y;
                acc.z += z * w[jj].z;
                acc.w += z * w[jj].w;
            }
            *(float4*)(out + ((size_t)bt * 28 + band) * 128 + d4) = acc;
        }
    }
}

extern "C" void kernel_launch(void* const* d_in, const int* in_sizes, int n_in,
                              void* d_out, int out_size, void* d_ws, size_t ws_size,
                              hipStream_t stream) {
    const float* x   = (const float*)d_in[0];
    const float* g1  = (const float*)d_in[1];
    const float* be1 = (const float*)d_in[2];
    const float* W1  = (const float*)d_in[3];
    const float* b1  = (const float*)d_in[4];
    const float* g2  = (const float*)d_in[5];
    const float* be2 = (const float*)d_in[6];
    const float* W2  = (const float*)d_in[7];
    const float* b2  = (const float*)d_in[8];
    const float* g3  = (const float*)d_in[9];
    const float* be3 = (const float*)d_in[10];
    const float* W3  = (const float*)d_in[11];
    const float* b3  = (const float*)d_in[12];
    float* out = (float*)d_out;

    float* wp = (float*)d_ws;          // 32768 floats of folded W
    float* bp = wp + 32768;            // 28*128 folded bias

    prep_kernel<<<dim3(28), dim3(128), 0, stream>>>(
        g1, be1, W1, b1, g2, be2, W2, b2, g3, be3, W3, b3, wp, bp);

    const int BT = in_sizes[0] / 257;  // 16000

    // C=4, R=4: 32 rows/block; C=8, R=4: 32 rows/block; C=16, R=2: 16 rows/block
    const int t32 = (BT + 31) / 32;    // 500
    const int t16 = (BT + 15) / 16;    // 1000
    bandsplit_stream<4, 4><<<dim3(8  * t32), dim3(256), 0, stream>>>(
        x, BT, wp,         bp, 0,   0,  8,  out);
    bandsplit_stream<8, 4><<<dim3(12 * t32), dim3(256), 0, stream>>>(
        x, BT, wp + 4096,  bp, 32,  8,  12, out);
    bandsplit_stream<16, 2><<<dim3(8 * t16), dim3(256), 0, stream>>>(
        x, BT, wp + 16384, bp, 128, 20, 8,  out);
}